// Round 6
// baseline (246.074 us; speedup 1.0000x reference)
//
#include <hip/hip_runtime.h>
#include <cstdint>
#include <cstddef>

#define B_   4
#define T_   2048
#define D_   1024
#define H_   8
#define DK_  64
#define HD_  512      // H*DK
#define CH_  64       // chunk length
#define NC_  32       // T_/CH_
#define EPS_ 1e-6f

typedef __attribute__((ext_vector_type(4))) float f32x4;
typedef __attribute__((ext_vector_type(8))) short s16x8;

__device__ __forceinline__ unsigned short f2bf(float f) {
    unsigned int x = __float_as_uint(f);
    unsigned int r = (x + 0x7FFFu + ((x >> 16) & 1u)) >> 16;
    return (unsigned short)r;
}
__device__ __forceinline__ float bf2f(unsigned short u) {
    return __uint_as_float(((unsigned int)u) << 16);
}
__device__ __forceinline__ void ld4(const float* p, float* o) {
    float4 v = *(const float4*)p; o[0]=v.x; o[1]=v.y; o[2]=v.z; o[3]=v.w;
}
// async global->LDS, 16B per lane; LDS dest = wave-uniform base + lane*16
__device__ __forceinline__ void gl_lds16(const unsigned short* g, unsigned short* l) {
    __builtin_amdgcn_global_load_lds(
        (const __attribute__((address_space(1))) unsigned int*)g,
        (__attribute__((address_space(3))) unsigned int*)l, 16, 0, 0);
}

// ---------------- K0: fused fp32 -> bf16 convert for all six tensors ----------------
__global__ __launch_bounds__(256) void k_cvt_all(
    const float* __restrict__ x,
    const float* __restrict__ wq, const float* __restrict__ wk,
    const float* __restrict__ wv, const float* __restrict__ wgw,
    const float* __restrict__ wo,
    unsigned short* __restrict__ xb,
    unsigned short* __restrict__ wqb, unsigned short* __restrict__ wkb,
    unsigned short* __restrict__ wvb, unsigned short* __restrict__ wgb,
    unsigned short* __restrict__ wob)
{
    int bid = blockIdx.x;
    const float* src; unsigned short* dst; int idx;
    if (bid < 8192) {
        src = x; dst = xb; idx = bid * 256 + threadIdx.x;
    } else {
        int r = bid - 8192;
        int w = r >> 9;
        idx = (r & 511) * 256 + threadIdx.x;
        switch (w) {
            case 0:  src = wq;  dst = wqb; break;
            case 1:  src = wk;  dst = wkb; break;
            case 2:  src = wv;  dst = wvb; break;
            case 3:  src = wgw; dst = wgb; break;
            default: src = wo;  dst = wob; break;
        }
    }
    float4 v = ((const float4*)src)[idx];
    ushort4 o;
    o.x = f2bf(v.x); o.y = f2bf(v.y); o.z = f2bf(v.z); o.w = f2bf(v.w);
    ((ushort4*)dst)[idx] = o;
}

// ---------------- K1: fused QKVG GEMM ----------------
// Block tile 256x128, wave tile 128x64 (8x4 accs) -> 42.7 FLOP per LDS byte.
// Single-buffered async staging + XOR swizzle. Grid 512, XCD-swizzled.
#define GBK  64
#define LDA  64   // unpadded: required by global_load_lds; XOR swizzle kills conflicts

__global__ __launch_bounds__(256, 2) void k_gemm_qkvg(
    const unsigned short* __restrict__ xb,
    const unsigned short* __restrict__ wqb, const unsigned short* __restrict__ wkb,
    const unsigned short* __restrict__ wvb, const unsigned short* __restrict__ wgb,
    const float* __restrict__ bias,
    unsigned short* __restrict__ qo, unsigned short* __restrict__ ko,
    unsigned short* __restrict__ vo, unsigned short* __restrict__ go)
{
    __shared__ unsigned short As[256 * LDA];   // 32 KB
    __shared__ unsigned short Bs[128 * LDA];   // 16 KB
    const int tid = threadIdx.x;
    const int id  = blockIdx.x;
    const int xcd = id & 7, per = id >> 3;       // per: 0..63
    const int mtile = xcd * 4 + (per & 3);       // 0..31
    const int combo = per >> 2;                  // 0..15
    const int which = combo >> 2;                // 0=Q 1=K 2=V 3=G
    const int nb    = combo & 3;
    const int m0    = mtile * 256;
    const int n0    = nb * 128;                  // within [0,512)
    const unsigned short* Wp = (which == 0) ? wqb : (which == 1) ? wkb : (which == 2) ? wvb : wgb;
    unsigned short* Op       = (which == 0) ? qo  : (which == 1) ? ko  : (which == 2) ? vo  : go;
    const int K = D_;
    const int NIT = K / GBK;                     // 16

    const int lane = tid & 63, wave = tid >> 6;
    const int wm = (wave >> 1) * 128, wn = (wave & 1) * 64;
    const int r16 = lane & 15, quad = lane >> 4;
    const int lrow = lane >> 3, lseg = lane & 7;   // staging: 8 rows x 8 segs per chunk
    const int sseg = lseg ^ lrow;                  // XOR swizzle
    const int rx   = r16 & 7;                      // read-side swizzle key

    f32x4 acc[8][4];
    #pragma unroll
    for (int a = 0; a < 8; a++)
        #pragma unroll
        for (int b = 0; b < 4; b++) acc[a][b] = 0.0f;

    for (int it = 0; it < NIT; ++it) {
        const int ko_ = it * GBK;
        #pragma unroll
        for (int i = 0; i < 8; i++) {            // A: 32 chunks, 8 per wave
            int chunk = wave * 8 + i;
            int row = chunk * 8 + lrow;
            gl_lds16(xb + (size_t)(m0 + row) * K + ko_ + sseg * 8, As + chunk * 512);
        }
        #pragma unroll
        for (int i = 0; i < 4; i++) {            // B: 16 chunks, 4 per wave
            int chunk = wave * 4 + i;
            int row = chunk * 8 + lrow;
            gl_lds16(Wp + (size_t)(n0 + row) * K + ko_ + sseg * 8, Bs + chunk * 512);
        }
        __syncthreads();
        #pragma unroll
        for (int kk = 0; kk < GBK; kk += 32) {
            const int gb_ = kk >> 3;             // granule base: 0 or 4
            const int goff = (((gb_ + quad) ^ rx) << 3);
            s16x8 af[8], bf[4];
            #pragma unroll
            for (int mt = 0; mt < 8; mt++)
                af[mt] = *(const s16x8*)&As[(wm + mt * 16 + r16) * LDA + goff];
            #pragma unroll
            for (int nt = 0; nt < 4; nt++)
                bf[nt] = *(const s16x8*)&Bs[(wn + nt * 16 + r16) * LDA + goff];
            #pragma unroll
            for (int mt = 0; mt < 8; mt++)
                #pragma unroll
                for (int nt = 0; nt < 4; nt++)
                    acc[mt][nt] = __builtin_amdgcn_mfma_f32_16x16x32_bf16(af[mt], bf[nt], acc[mt][nt], 0, 0, 0);
        }
        __syncthreads();
    }
    #pragma unroll
    for (int mt = 0; mt < 8; mt++) {
        #pragma unroll
        for (int nt = 0; nt < 4; nt++) {
            int col = n0 + wn + nt * 16 + r16;
            float bv = (which == 3) ? bias[col] : 0.0f;
            #pragma unroll
            for (int r = 0; r < 4; r++) {
                int row = m0 + wm + mt * 16 + quad * 4 + r;
                float v = acc[mt][nt][r];
                if (which <= 1)      v = (v > 0.0f) ? v + 1.0f : __builtin_expf(v);     // phi = elu+1
                else if (which == 3) v = 1.0f / (1.0f + __builtin_expf(-(v + bv)));     // sigmoid gate
                Op[(size_t)row * HD_ + col] = f2bf(v);
            }
        }
    }
}

// ---------------- K5: output GEMM: Y = OG @ W_O^T (fp32 out), single-buffered 128x128 ----------------
__global__ __launch_bounds__(256) void k_gemm_out(
    const unsigned short* __restrict__ ogb, const unsigned short* __restrict__ wob,
    float* __restrict__ y)
{
    __shared__ unsigned short As[128 * LDA];
    __shared__ unsigned short Bs[128 * LDA];
    const int tid = threadIdx.x;
    const int id  = blockIdx.x;
    const int xcd = id & 7, per = id >> 3;
    const int m0 = (xcd * 8 + (per & 7)) * 128;
    const int n0 = (per >> 3) * 128;             // 0..7 n-tiles (D_=1024)
    const int K = HD_;   // 512

    const int lane = tid & 63, wave = tid >> 6;
    const int wm = (wave >> 1) * 64, wn = (wave & 1) * 64;
    const int r16 = lane & 15, quad = lane >> 4;
    const int lrow = lane >> 3, lseg = lane & 7;
    const int sseg = lseg ^ lrow;
    const int rx   = r16 & 7;

    f32x4 acc[4][4];
    #pragma unroll
    for (int a = 0; a < 4; a++)
        #pragma unroll
        for (int b = 0; b < 4; b++) acc[a][b] = 0.0f;

    for (int ko_ = 0; ko_ < K; ko_ += GBK) {
        #pragma unroll
        for (int i = 0; i < 4; i++) {
            int chunk = wave * 4 + i;
            int row = chunk * 8 + lrow;
            gl_lds16(ogb + (size_t)(m0 + row) * K + ko_ + sseg * 8, As + chunk * 512);
            gl_lds16(wob + (size_t)(n0 + row) * K + ko_ + sseg * 8, Bs + chunk * 512);
        }
        __syncthreads();
        #pragma unroll
        for (int kk = 0; kk < GBK; kk += 32) {
            const int gb_ = kk >> 3;
            const int goff = (((gb_ + quad) ^ rx) << 3);
            s16x8 af[4], bf[4];
            #pragma unroll
            for (int mt = 0; mt < 4; mt++)
                af[mt] = *(const s16x8*)&As[(wm + mt * 16 + r16) * LDA + goff];
            #pragma unroll
            for (int nt = 0; nt < 4; nt++)
                bf[nt] = *(const s16x8*)&Bs[(wn + nt * 16 + r16) * LDA + goff];
            #pragma unroll
            for (int mt = 0; mt < 4; mt++)
                #pragma unroll
                for (int nt = 0; nt < 4; nt++)
                    acc[mt][nt] = __builtin_amdgcn_mfma_f32_16x16x32_bf16(af[mt], bf[nt], acc[mt][nt], 0, 0, 0);
        }
        __syncthreads();
    }
    #pragma unroll
    for (int mt = 0; mt < 4; mt++)
        #pragma unroll
        for (int nt = 0; nt < 4; nt++) {
            int col = n0 + wn + nt * 16 + r16;
            #pragma unroll
            for (int r = 0; r < 4; r++) {
                int row = m0 + wm + mt * 16 + quad * 4 + r;
                y[(size_t)row * D_ + col] = acc[mt][nt][r];
            }
        }
}

// ---------------- K2: per-chunk decayed sums (RAW, no scan) ----------------
// Ssum[bh,c][i][j] = sum_l gamma^(CH-1-l) k_l[i] v_l[j];  zsum likewise.
__global__ __launch_bounds__(256) void k_chunk_sums(
    const unsigned short* __restrict__ Kb, const unsigned short* __restrict__ Vb,
    float* __restrict__ Ssum, float* __restrict__ zsum, const float* __restrict__ decay_log)
{
    __shared__ float kl[CH_ * 68];
    __shared__ float vl[CH_ * 68];
    const int tid = threadIdx.x;
    const int bc  = blockIdx.x;            // bh*NC_ + c
    const int c   = bc & (NC_ - 1);
    const int bh  = bc >> 5;
    const int h   = bh & (H_ - 1);
    const int b   = bh >> 3;
    const float g  = 1.0f / (1.0f + __builtin_expf(-decay_log[h]));
    const float lg = __builtin_log2f(g);
    const int t0 = c * CH_;

    #pragma unroll
    for (int e = 0; e < 2; e++) {
        int lid = e * 256 + tid;           // 0..511 : 64 rows x 8 segs
        int l = lid >> 3, d0 = (lid & 7) * 8;
        float w = __builtin_exp2f((float)(CH_ - 1 - l) * lg);
        size_t gidx = (size_t)(b * T_ + t0 + l) * HD_ + h * DK_ + d0;
        uint4 kraw = *(const uint4*)(Kb + gidx);
        uint4 vraw = *(const uint4*)(Vb + gidx);
        const unsigned short* kp = (const unsigned short*)&kraw;
        const unsigned short* vp = (const unsigned short*)&vraw;
        #pragma unroll
        for (int j = 0; j < 8; j++) {
            kl[l * 68 + d0 + j] = bf2f(kp[j]) * w;   // decay folded into k
            vl[l * 68 + d0 + j] = bf2f(vp[j]);
        }
    }
    __syncthreads();

    const int ti = tid >> 4, tj = tid & 15;
    const int i0 = ti * 4, j0 = tj * 4;
    float acc[4][4];
    #pragma unroll
    for (int r = 0; r < 4; r++)
        #pragma unroll
        for (int cc = 0; cc < 4; cc++) acc[r][cc] = 0.0f;

    for (int l = 0; l < CH_; l++) {
        float kv[4], vv[4];
        ld4(&kl[l * 68 + i0], kv);
        ld4(&vl[l * 68 + j0], vv);
        #pragma unroll
        for (int r = 0; r < 4; r++)
            #pragma unroll
            for (int cc = 0; cc < 4; cc++) acc[r][cc] += kv[r] * vv[cc];
    }
    size_t base = (size_t)bc * (DK_ * DK_);
    #pragma unroll
    for (int r = 0; r < 4; r++) {
        float4 st = make_float4(acc[r][0], acc[r][1], acc[r][2], acc[r][3]);
        *(float4*)&Ssum[base + (size_t)(i0 + r) * DK_ + j0] = st;
    }
    if (tid < DK_) {
        float s = 0.0f;
        for (int l = 0; l < CH_; l++) s += kl[l * 68 + tid];
        zsum[(size_t)bc * DK_ + tid] = s;
    }
}

// ---------------- K4: per-chunk outputs; computes its OWN decayed prefix (scan fused) ----------------
__global__ __launch_bounds__(256) void k_chunk_out(
    const unsigned short* __restrict__ Qb, const unsigned short* __restrict__ Kb,
    const unsigned short* __restrict__ Vb, const unsigned short* __restrict__ Gb,
    const float* __restrict__ Ssum, const float* __restrict__ zsum,
    unsigned short* __restrict__ OGb, const float* __restrict__ decay_log)
{
    __shared__ float BufA[CH_ * 68];   // qT, later scT
    __shared__ float BufB[CH_ * 68];   // kT, later v
    __shared__ float BufC[CH_ * 68];   // S_prev (rows = k-dim, cols = v-dim)
    __shared__ float den_l[CH_];
    __shared__ float zp_l[DK_];
    __shared__ float gpow[CH_ + 1];

    const int tid = threadIdx.x;
    const int bc  = blockIdx.x;
    const int c   = bc & (NC_ - 1);
    const int bh  = bc >> 5;
    const int h   = bh & (H_ - 1);
    const int b   = bh >> 3;
    const float g  = 1.0f / (1.0f + __builtin_expf(-decay_log[h]));
    const float lg = __builtin_log2f(g);
    const float gC = __builtin_exp2f((float)CH_ * lg);   // gamma^CH
    const int t0 = c * CH_;

    if (tid <= CH_) gpow[tid] = __builtin_exp2f((float)tid * lg);

    // ---- self-computed exclusive prefix: S_prev = sum_{c'<c} gC^(c-1-c') Ssum[c'] (Horner)
    {
        f32x4 sp[4];
        #pragma unroll
        for (int q = 0; q < 4; q++) sp[q] = 0.0f;
        const int flat = tid * 16;
        for (int cp = 0; cp < c; cp++) {
            const float* src = Ssum + (size_t)(bh * NC_ + cp) * 4096 + flat;
            #pragma unroll
            for (int q = 0; q < 4; q++) {
                f32x4 v = *(const f32x4*)(src + q * 4);
                sp[q] = sp[q] * gC + v;
            }
        }
        int row = tid >> 2, col0 = (tid & 3) * 16;
        #pragma unroll
        for (int q = 0; q < 4; q++)
            *(f32x4*)&BufC[row * 68 + col0 + q * 4] = sp[q];
    }
    if (tid < DK_) {
        float zp = 0.0f;
        for (int cp = 0; cp < c; cp++)
            zp = zp * gC + zsum[(size_t)(bh * NC_ + cp) * DK_ + tid];
        zp_l[tid] = zp;
    }

    // load q,k transposed: Buf[d][l]
    #pragma unroll
    for (int e = 0; e < 2; e++) {
        int lid = e * 256 + tid;
        int l = lid >> 3, d0 = (lid & 7) * 8;
        size_t gidx = (size_t)(b * T_ + t0 + l) * HD_ + h * DK_ + d0;
        uint4 qraw = *(const uint4*)(Qb + gidx);
        uint4 kraw = *(const uint4*)(Kb + gidx);
        const unsigned short* qp = (const unsigned short*)&qraw;
        const unsigned short* kp = (const unsigned short*)&kraw;
        #pragma unroll
        for (int j = 0; j < 8; j++) {
            BufA[(d0 + j) * 68 + l] = bf2f(qp[j]);
            BufB[(d0 + j) * 68 + l] = bf2f(kp[j]);
        }
    }
    __syncthreads();

    const int ti = tid >> 4, tj = tid & 15;
    const int i0 = ti * 4, j0 = tj * 4;
    float sc[4][4], it[4][4];
    #pragma unroll
    for (int r = 0; r < 4; r++)
        #pragma unroll
        for (int cc = 0; cc < 4; cc++) { sc[r][cc] = 0.0f; it[r][cc] = 0.0f; }

    for (int d = 0; d < DK_; d++) {
        float qv[4], kv[4], sv[4];
        ld4(&BufA[d * 68 + i0], qv);
        ld4(&BufB[d * 68 + j0], kv);
        ld4(&BufC[d * 68 + j0], sv);
        #pragma unroll
        for (int r = 0; r < 4; r++)
            #pragma unroll
            for (int cc = 0; cc < 4; cc++) {
                sc[r][cc] += qv[r] * kv[cc];
                it[r][cc] += qv[r] * sv[cc];
            }
    }
    // decay weights, causal mask, row sums for denominator
    #pragma unroll
    for (int r = 0; r < 4; r++) {
        int i = i0 + r;
        #pragma unroll
        for (int cc = 0; cc < 4; cc++) {
            int jl = j0 + cc;
            sc[r][cc] = (jl <= i) ? sc[r][cc] * gpow[i - jl] : 0.0f;
            it[r][cc] *= gpow[i + 1];
        }
        float rs = sc[r][0] + sc[r][1] + sc[r][2] + sc[r][3];
        rs += __shfl_xor(rs, 1);
        rs += __shfl_xor(rs, 2);
        rs += __shfl_xor(rs, 4);
        rs += __shfl_xor(rs, 8);
        if (tj == 0) den_l[i] = rs;   // intra part
    }
    __syncthreads();
    if (tid < DK_) {                  // + gamma^(i+1) * q_i . z_prev + eps
        float dp = 0.0f;
        for (int d = 0; d < DK_; d++) dp += BufA[d * 68 + tid] * zp_l[d];
        den_l[tid] += gpow[tid + 1] * dp + EPS_;
    }
    __syncthreads();
    // write scT into BufA; load v into BufB
    #pragma unroll
    for (int cc = 0; cc < 4; cc++) {
        float4 st = make_float4(sc[0][cc], sc[1][cc], sc[2][cc], sc[3][cc]);
        *(float4*)&BufA[(j0 + cc) * 68 + i0] = st;
    }
    #pragma unroll
    for (int e = 0; e < 2; e++) {
        int lid = e * 256 + tid;
        int l = lid >> 3, d0 = (lid & 7) * 8;
        size_t gidx = (size_t)(b * T_ + t0 + l) * HD_ + h * DK_ + d0;
        uint4 vraw = *(const uint4*)(Vb + gidx);
        const unsigned short* vp = (const unsigned short*)&vraw;
        #pragma unroll
        for (int j = 0; j < 8; j++) BufB[l * 68 + d0 + j] = bf2f(vp[j]);
    }
    __syncthreads();

    float og[4][4];
    #pragma unroll
    for (int r = 0; r < 4; r++)
        #pragma unroll
        for (int cc = 0; cc < 4; cc++) og[r][cc] = it[r][cc];

    for (int jl = 0; jl < CH_; jl++) {
        float scv[4], vv[4];
        ld4(&BufA[jl * 68 + i0], scv);
        ld4(&BufB[jl * 68 + j0], vv);
        #pragma unroll
        for (int r = 0; r < 4; r++)
            #pragma unroll
            for (int cc = 0; cc < 4; cc++) og[r][cc] += scv[r] * vv[cc];
    }
    #pragma unroll
    for (int r = 0; r < 4; r++) {
        int i = i0 + r;
        float rcp = 1.0f / den_l[i];
        size_t gidx = (size_t)(b * T_ + t0 + i) * HD_ + h * DK_ + j0;
        ushort4 graw = *(const ushort4*)(Gb + gidx);
        ushort4 o;
        o.x = f2bf(og[r][0] * rcp * bf2f(graw.x));
        o.y = f2bf(og[r][1] * rcp * bf2f(graw.y));
        o.z = f2bf(og[r][2] * rcp * bf2f(graw.z));
        o.w = f2bf(og[r][3] * rcp * bf2f(graw.w));
        *(ushort4*)(OGb + gidx) = o;
    }
}

// ---------------- host ----------------
extern "C" void kernel_launch(void* const* d_in, const int* in_sizes, int n_in,
                              void* d_out, int out_size, void* d_ws, size_t ws_size,
                              hipStream_t stream)
{
    (void)in_sizes; (void)n_in; (void)out_size; (void)ws_size;
    const float* x         = (const float*)d_in[0];
    const float* W_Q       = (const float*)d_in[1];
    const float* W_K       = (const float*)d_in[2];
    const float* W_V       = (const float*)d_in[3];
    const float* W_gw      = (const float*)d_in[4];
    const float* W_gb      = (const float*)d_in[5];
    const float* W_O       = (const float*)d_in[6];
    const float* decay_log = (const float*)d_in[7];
    float* y = (float*)d_out;

    char* ws = (char*)d_ws;
    size_t off = 0;
    auto alloc = [&](size_t bytes) { void* p = ws + off; off += (bytes + 255) & ~(size_t)255; return p; };
    unsigned short* xb   = (unsigned short*)alloc((size_t)B_ * T_ * D_ * 2);
    unsigned short* wqb  = (unsigned short*)alloc((size_t)HD_ * D_ * 2);
    unsigned short* wkb  = (unsigned short*)alloc((size_t)HD_ * D_ * 2);
    unsigned short* wvb  = (unsigned short*)alloc((size_t)HD_ * D_ * 2);
    unsigned short* wgb  = (unsigned short*)alloc((size_t)HD_ * D_ * 2);
    unsigned short* wob  = (unsigned short*)alloc((size_t)D_ * HD_ * 2);
    unsigned short* qb   = (unsigned short*)alloc((size_t)B_ * T_ * HD_ * 2);
    unsigned short* kb   = (unsigned short*)alloc((size_t)B_ * T_ * HD_ * 2);
    unsigned short* vb   = (unsigned short*)alloc((size_t)B_ * T_ * HD_ * 2);
    unsigned short* gb   = (unsigned short*)alloc((size_t)B_ * T_ * HD_ * 2);
    unsigned short* ogb  = (unsigned short*)alloc((size_t)B_ * T_ * HD_ * 2);
    float* Ssum = (float*)alloc((size_t)B_ * H_ * NC_ * DK_ * DK_ * 4);
    float* zsum = (float*)alloc((size_t)B_ * H_ * NC_ * DK_ * 4);

    k_cvt_all<<<8192 + 5 * 512, 256, 0, stream>>>(x, W_Q, W_K, W_V, W_gw, W_O,
                                                  xb, wqb, wkb, wvb, wgb, wob);
    k_gemm_qkvg<<<512, 256, 0, stream>>>(xb, wqb, wkb, wvb, wgb, W_gb, qb, kb, vb, gb);
    k_chunk_sums<<<B_ * H_ * NC_, 256, 0, stream>>>(kb, vb, Ssum, zsum, decay_log);
    k_chunk_out<<<B_ * H_ * NC_, 256, 0, stream>>>(qb, kb, vb, gb, Ssum, zsum, ogb, decay_log);
    k_gemm_out<<<512, 256, 0, stream>>>(ogb, wob, y);
}

// Round 7
// 242.912 us; speedup vs baseline: 1.0130x; 1.0130x over previous
//
#include <hip/hip_runtime.h>
#include <cstdint>
#include <cstddef>

#define B_   4
#define T_   2048
#define D_   1024
#define H_   8
#define DK_  64
#define HD_  512      // H*DK
#define CH_  64       // chunk length
#define NC_  32       // T_/CH_
#define EPS_ 1e-6f

typedef __attribute__((ext_vector_type(4))) float f32x4;
typedef __attribute__((ext_vector_type(8))) short s16x8;

__device__ __forceinline__ unsigned short f2bf(float f) {
    unsigned int x = __float_as_uint(f);
    unsigned int r = (x + 0x7FFFu + ((x >> 16) & 1u)) >> 16;
    return (unsigned short)r;
}
__device__ __forceinline__ float bf2f(unsigned short u) {
    return __uint_as_float(((unsigned int)u) << 16);
}
__device__ __forceinline__ void ld4(const float* p, float* o) {
    float4 v = *(const float4*)p; o[0]=v.x; o[1]=v.y; o[2]=v.z; o[3]=v.w;
}
// async global->LDS, 16B per lane; LDS dest = wave-uniform base + lane*16
__device__ __forceinline__ void gl_lds16(const unsigned short* g, unsigned short* l) {
    __builtin_amdgcn_global_load_lds(
        (const __attribute__((address_space(1))) unsigned int*)g,
        (__attribute__((address_space(3))) unsigned int*)l, 16, 0, 0);
}

// ---------------- K0: fused fp32 -> bf16 convert for all six tensors ----------------
__global__ __launch_bounds__(256) void k_cvt_all(
    const float* __restrict__ x,
    const float* __restrict__ wq, const float* __restrict__ wk,
    const float* __restrict__ wv, const float* __restrict__ wgw,
    const float* __restrict__ wo,
    unsigned short* __restrict__ xb,
    unsigned short* __restrict__ wqb, unsigned short* __restrict__ wkb,
    unsigned short* __restrict__ wvb, unsigned short* __restrict__ wgb,
    unsigned short* __restrict__ wob)
{
    int bid = blockIdx.x;
    const float* src; unsigned short* dst; int idx;
    if (bid < 8192) {
        src = x; dst = xb; idx = bid * 256 + threadIdx.x;
    } else {
        int r = bid - 8192;
        int w = r >> 9;
        idx = (r & 511) * 256 + threadIdx.x;
        switch (w) {
            case 0:  src = wq;  dst = wqb; break;
            case 1:  src = wk;  dst = wkb; break;
            case 2:  src = wv;  dst = wvb; break;
            case 3:  src = wgw; dst = wgb; break;
            default: src = wo;  dst = wob; break;
        }
    }
    float4 v = ((const float4*)src)[idx];
    ushort4 o;
    o.x = f2bf(v.x); o.y = f2bf(v.y); o.z = f2bf(v.z); o.w = f2bf(v.w);
    ((ushort4*)dst)[idx] = o;
}

// ---------------- K1: fused QKVG GEMM (round-4 proven config) ----------------
// 128x128 block tile, 4x4 acc/wave, single-buffer async staging + XOR swizzle,
// XCD-swizzled 1D grid 1024. ~5 blocks/CU co-resident does the latency hiding.
#define GT_M 128
#define GT_N 128
#define GBK  64
#define LDA  64   // unpadded: required by global_load_lds; XOR swizzle kills conflicts

__global__ __launch_bounds__(256) void k_gemm_qkvg(
    const unsigned short* __restrict__ xb,
    const unsigned short* __restrict__ wqb, const unsigned short* __restrict__ wkb,
    const unsigned short* __restrict__ wvb, const unsigned short* __restrict__ wgb,
    const float* __restrict__ bias,
    unsigned short* __restrict__ qo, unsigned short* __restrict__ ko,
    unsigned short* __restrict__ vo, unsigned short* __restrict__ go)
{
    __shared__ unsigned short As[GT_M * LDA];
    __shared__ unsigned short Bs[GT_N * LDA];
    const int tid = threadIdx.x;
    const int id  = blockIdx.x;
    const int xcd = id & 7, per = id >> 3;
    const int mtile = xcd * 8 + (per & 7);       // 0..63
    const int combo = per >> 3;                  // 0..15
    const int which = combo >> 2;                // 0=Q 1=K 2=V 3=G
    const int nb    = combo & 3;
    const int m0    = mtile * GT_M;
    const int n0    = nb * GT_N;                 // within [0,512)
    const unsigned short* Wp = (which == 0) ? wqb : (which == 1) ? wkb : (which == 2) ? wvb : wgb;
    unsigned short* Op       = (which == 0) ? qo  : (which == 1) ? ko  : (which == 2) ? vo  : go;
    const int K = D_;

    const int lane = tid & 63, wave = tid >> 6;
    const int wm = (wave >> 1) * 64, wn = (wave & 1) * 64;
    const int r16 = lane & 15, quad = lane >> 4;
    const int lrow = lane >> 3, lseg = lane & 7;   // staging: 8 rows x 8 segs per wave-chunk
    const int sseg = lseg ^ lrow;                  // XOR swizzle
    const int rx   = r16 & 7;                      // read-side swizzle key

    f32x4 acc[4][4];
    #pragma unroll
    for (int a = 0; a < 4; a++)
        #pragma unroll
        for (int b = 0; b < 4; b++) acc[a][b] = 0.0f;

    for (int ko_ = 0; ko_ < K; ko_ += GBK) {
        #pragma unroll
        for (int i = 0; i < 4; i++) {
            int chunk = wave * 4 + i;            // 0..15, wave-uniform
            int row = chunk * 8 + lrow;
            gl_lds16(xb + (size_t)(m0 + row) * K + ko_ + sseg * 8, As + chunk * 512);
            gl_lds16(Wp + (size_t)(n0 + row) * K + ko_ + sseg * 8, Bs + chunk * 512);
        }
        __syncthreads();
        #pragma unroll
        for (int kk = 0; kk < GBK; kk += 32) {
            const int gb_ = kk >> 3;             // granule base: 0 or 4
            const int goff = (((gb_ + quad) ^ rx) << 3);
            s16x8 af[4], bf[4];
            #pragma unroll
            for (int mt = 0; mt < 4; mt++)
                af[mt] = *(const s16x8*)&As[(wm + mt * 16 + r16) * LDA + goff];
            #pragma unroll
            for (int nt = 0; nt < 4; nt++)
                bf[nt] = *(const s16x8*)&Bs[(wn + nt * 16 + r16) * LDA + goff];
            #pragma unroll
            for (int mt = 0; mt < 4; mt++)
                #pragma unroll
                for (int nt = 0; nt < 4; nt++)
                    acc[mt][nt] = __builtin_amdgcn_mfma_f32_16x16x32_bf16(af[mt], bf[nt], acc[mt][nt], 0, 0, 0);
        }
        __syncthreads();
    }
    #pragma unroll
    for (int mt = 0; mt < 4; mt++) {
        #pragma unroll
        for (int nt = 0; nt < 4; nt++) {
            int col = n0 + wn + nt * 16 + r16;
            float bv = (which == 3) ? bias[col] : 0.0f;
            #pragma unroll
            for (int r = 0; r < 4; r++) {
                int row = m0 + wm + mt * 16 + quad * 4 + r;
                float v = acc[mt][nt][r];
                if (which <= 1)      v = (v > 0.0f) ? v + 1.0f : __builtin_expf(v);     // phi = elu+1
                else if (which == 3) v = 1.0f / (1.0f + __builtin_expf(-(v + bv)));     // sigmoid gate
                Op[(size_t)row * HD_ + col] = f2bf(v);
            }
        }
    }
}

// ---------------- K5: output GEMM: Y = OG @ W_O^T (fp32 out), round-4 config ----------------
__global__ __launch_bounds__(256) void k_gemm_out(
    const unsigned short* __restrict__ ogb, const unsigned short* __restrict__ wob,
    float* __restrict__ y)
{
    __shared__ unsigned short As[GT_M * LDA];
    __shared__ unsigned short Bs[GT_N * LDA];
    const int tid = threadIdx.x;
    const int id  = blockIdx.x;
    const int xcd = id & 7, per = id >> 3;
    const int m0 = (xcd * 8 + (per & 7)) * GT_M;
    const int n0 = (per >> 3) * GT_N;            // 0..7 n-tiles (D_=1024)
    const int K = HD_;   // 512

    const int lane = tid & 63, wave = tid >> 6;
    const int wm = (wave >> 1) * 64, wn = (wave & 1) * 64;
    const int r16 = lane & 15, quad = lane >> 4;
    const int lrow = lane >> 3, lseg = lane & 7;
    const int sseg = lseg ^ lrow;
    const int rx   = r16 & 7;

    f32x4 acc[4][4];
    #pragma unroll
    for (int a = 0; a < 4; a++)
        #pragma unroll
        for (int b = 0; b < 4; b++) acc[a][b] = 0.0f;

    for (int ko_ = 0; ko_ < K; ko_ += GBK) {
        #pragma unroll
        for (int i = 0; i < 4; i++) {
            int chunk = wave * 4 + i;
            int row = chunk * 8 + lrow;
            gl_lds16(ogb + (size_t)(m0 + row) * K + ko_ + sseg * 8, As + chunk * 512);
            gl_lds16(wob + (size_t)(n0 + row) * K + ko_ + sseg * 8, Bs + chunk * 512);
        }
        __syncthreads();
        #pragma unroll
        for (int kk = 0; kk < GBK; kk += 32) {
            const int gb_ = kk >> 3;
            const int goff = (((gb_ + quad) ^ rx) << 3);
            s16x8 af[4], bf[4];
            #pragma unroll
            for (int mt = 0; mt < 4; mt++)
                af[mt] = *(const s16x8*)&As[(wm + mt * 16 + r16) * LDA + goff];
            #pragma unroll
            for (int nt = 0; nt < 4; nt++)
                bf[nt] = *(const s16x8*)&Bs[(wn + nt * 16 + r16) * LDA + goff];
            #pragma unroll
            for (int mt = 0; mt < 4; mt++)
                #pragma unroll
                for (int nt = 0; nt < 4; nt++)
                    acc[mt][nt] = __builtin_amdgcn_mfma_f32_16x16x32_bf16(af[mt], bf[nt], acc[mt][nt], 0, 0, 0);
        }
        __syncthreads();
    }
    #pragma unroll
    for (int mt = 0; mt < 4; mt++)
        #pragma unroll
        for (int nt = 0; nt < 4; nt++) {
            int col = n0 + wn + nt * 16 + r16;
            #pragma unroll
            for (int r = 0; r < 4; r++) {
                int row = m0 + wm + mt * 16 + quad * 4 + r;
                y[(size_t)row * D_ + col] = acc[mt][nt][r];
            }
        }
}

// ---------------- K2: per-chunk decayed sums (RAW, no scan) ----------------
// Ssum[bh,c][i][j] = sum_l gamma^(CH-1-l) k_l[i] v_l[j];  zsum likewise.
__global__ __launch_bounds__(256) void k_chunk_sums(
    const unsigned short* __restrict__ Kb, const unsigned short* __restrict__ Vb,
    float* __restrict__ Ssum, float* __restrict__ zsum, const float* __restrict__ decay_log)
{
    __shared__ float kl[CH_ * 68];
    __shared__ float vl[CH_ * 68];
    const int tid = threadIdx.x;
    const int bc  = blockIdx.x;            // bh*NC_ + c
    const int c   = bc & (NC_ - 1);
    const int bh  = bc >> 5;
    const int h   = bh & (H_ - 1);
    const int b   = bh >> 3;
    const float g  = 1.0f / (1.0f + __builtin_expf(-decay_log[h]));
    const float lg = __builtin_log2f(g);
    const int t0 = c * CH_;

    #pragma unroll
    for (int e = 0; e < 2; e++) {
        int lid = e * 256 + tid;           // 0..511 : 64 rows x 8 segs
        int l = lid >> 3, d0 = (lid & 7) * 8;
        float w = __builtin_exp2f((float)(CH_ - 1 - l) * lg);
        size_t gidx = (size_t)(b * T_ + t0 + l) * HD_ + h * DK_ + d0;
        uint4 kraw = *(const uint4*)(Kb + gidx);
        uint4 vraw = *(const uint4*)(Vb + gidx);
        const unsigned short* kp = (const unsigned short*)&kraw;
        const unsigned short* vp = (const unsigned short*)&vraw;
        #pragma unroll
        for (int j = 0; j < 8; j++) {
            kl[l * 68 + d0 + j] = bf2f(kp[j]) * w;   // decay folded into k
            vl[l * 68 + d0 + j] = bf2f(vp[j]);
        }
    }
    __syncthreads();

    const int ti = tid >> 4, tj = tid & 15;
    const int i0 = ti * 4, j0 = tj * 4;
    float acc[4][4];
    #pragma unroll
    for (int r = 0; r < 4; r++)
        #pragma unroll
        for (int cc = 0; cc < 4; cc++) acc[r][cc] = 0.0f;

    for (int l = 0; l < CH_; l++) {
        float kv[4], vv[4];
        ld4(&kl[l * 68 + i0], kv);
        ld4(&vl[l * 68 + j0], vv);
        #pragma unroll
        for (int r = 0; r < 4; r++)
            #pragma unroll
            for (int cc = 0; cc < 4; cc++) acc[r][cc] += kv[r] * vv[cc];
    }
    size_t base = (size_t)bc * (DK_ * DK_);
    #pragma unroll
    for (int r = 0; r < 4; r++) {
        float4 st = make_float4(acc[r][0], acc[r][1], acc[r][2], acc[r][3]);
        *(float4*)&Ssum[base + (size_t)(i0 + r) * DK_ + j0] = st;
    }
    if (tid < DK_) {
        float s = 0.0f;
        for (int l = 0; l < CH_; l++) s += kl[l * 68 + tid];
        zsum[(size_t)bc * DK_ + tid] = s;
    }
}

// ---------------- K4: per-chunk outputs; computes its OWN decayed prefix (scan fused) ----------------
__global__ __launch_bounds__(256) void k_chunk_out(
    const unsigned short* __restrict__ Qb, const unsigned short* __restrict__ Kb,
    const unsigned short* __restrict__ Vb, const unsigned short* __restrict__ Gb,
    const float* __restrict__ Ssum, const float* __restrict__ zsum,
    unsigned short* __restrict__ OGb, const float* __restrict__ decay_log)
{
    __shared__ float BufA[CH_ * 68];   // qT, later scT
    __shared__ float BufB[CH_ * 68];   // kT, later v
    __shared__ float BufC[CH_ * 68];   // S_prev (rows = k-dim, cols = v-dim)
    __shared__ float den_l[CH_];
    __shared__ float zp_l[DK_];
    __shared__ float gpow[CH_ + 1];

    const int tid = threadIdx.x;
    const int bc  = blockIdx.x;
    const int c   = bc & (NC_ - 1);
    const int bh  = bc >> 5;
    const int h   = bh & (H_ - 1);
    const int b   = bh >> 3;
    const float g  = 1.0f / (1.0f + __builtin_expf(-decay_log[h]));
    const float lg = __builtin_log2f(g);
    const float gC = __builtin_exp2f((float)CH_ * lg);   // gamma^CH
    const int t0 = c * CH_;

    if (tid <= CH_) gpow[tid] = __builtin_exp2f((float)tid * lg);

    // ---- self-computed exclusive prefix: S_prev = sum_{c'<c} gC^(c-1-c') Ssum[c'] (Horner)
    {
        f32x4 sp[4];
        #pragma unroll
        for (int q = 0; q < 4; q++) sp[q] = 0.0f;
        const int flat = tid * 16;
        for (int cp = 0; cp < c; cp++) {
            const float* src = Ssum + (size_t)(bh * NC_ + cp) * 4096 + flat;
            #pragma unroll
            for (int q = 0; q < 4; q++) {
                f32x4 v = *(const f32x4*)(src + q * 4);
                sp[q] = sp[q] * gC + v;
            }
        }
        int row = tid >> 2, col0 = (tid & 3) * 16;
        #pragma unroll
        for (int q = 0; q < 4; q++)
            *(f32x4*)&BufC[row * 68 + col0 + q * 4] = sp[q];
    }
    if (tid < DK_) {
        float zp = 0.0f;
        for (int cp = 0; cp < c; cp++)
            zp = zp * gC + zsum[(size_t)(bh * NC_ + cp) * DK_ + tid];
        zp_l[tid] = zp;
    }

    // load q,k transposed: Buf[d][l]
    #pragma unroll
    for (int e = 0; e < 2; e++) {
        int lid = e * 256 + tid;
        int l = lid >> 3, d0 = (lid & 7) * 8;
        size_t gidx = (size_t)(b * T_ + t0 + l) * HD_ + h * DK_ + d0;
        uint4 qraw = *(const uint4*)(Qb + gidx);
        uint4 kraw = *(const uint4*)(Kb + gidx);
        const unsigned short* qp = (const unsigned short*)&qraw;
        const unsigned short* kp = (const unsigned short*)&kraw;
        #pragma unroll
        for (int j = 0; j < 8; j++) {
            BufA[(d0 + j) * 68 + l] = bf2f(qp[j]);
            BufB[(d0 + j) * 68 + l] = bf2f(kp[j]);
        }
    }
    __syncthreads();

    const int ti = tid >> 4, tj = tid & 15;
    const int i0 = ti * 4, j0 = tj * 4;
    float sc[4][4], it[4][4];
    #pragma unroll
    for (int r = 0; r < 4; r++)
        #pragma unroll
        for (int cc = 0; cc < 4; cc++) { sc[r][cc] = 0.0f; it[r][cc] = 0.0f; }

    for (int d = 0; d < DK_; d++) {
        float qv[4], kv[4], sv[4];
        ld4(&BufA[d * 68 + i0], qv);
        ld4(&BufB[d * 68 + j0], kv);
        ld4(&BufC[d * 68 + j0], sv);
        #pragma unroll
        for (int r = 0; r < 4; r++)
            #pragma unroll
            for (int cc = 0; cc < 4; cc++) {
                sc[r][cc] += qv[r] * kv[cc];
                it[r][cc] += qv[r] * sv[cc];
            }
    }
    // decay weights, causal mask, row sums for denominator
    #pragma unroll
    for (int r = 0; r < 4; r++) {
        int i = i0 + r;
        #pragma unroll
        for (int cc = 0; cc < 4; cc++) {
            int jl = j0 + cc;
            sc[r][cc] = (jl <= i) ? sc[r][cc] * gpow[i - jl] : 0.0f;
            it[r][cc] *= gpow[i + 1];
        }
        float rs = sc[r][0] + sc[r][1] + sc[r][2] + sc[r][3];
        rs += __shfl_xor(rs, 1);
        rs += __shfl_xor(rs, 2);
        rs += __shfl_xor(rs, 4);
        rs += __shfl_xor(rs, 8);
        if (tj == 0) den_l[i] = rs;   // intra part
    }
    __syncthreads();
    if (tid < DK_) {                  // + gamma^(i+1) * q_i . z_prev + eps
        float dp = 0.0f;
        for (int d = 0; d < DK_; d++) dp += BufA[d * 68 + tid] * zp_l[d];
        den_l[tid] += gpow[tid + 1] * dp + EPS_;
    }
    __syncthreads();
    // write scT into BufA; load v into BufB
    #pragma unroll
    for (int cc = 0; cc < 4; cc++) {
        float4 st = make_float4(sc[0][cc], sc[1][cc], sc[2][cc], sc[3][cc]);
        *(float4*)&BufA[(j0 + cc) * 68 + i0] = st;
    }
    #pragma unroll
    for (int e = 0; e < 2; e++) {
        int lid = e * 256 + tid;
        int l = lid >> 3, d0 = (lid & 7) * 8;
        size_t gidx = (size_t)(b * T_ + t0 + l) * HD_ + h * DK_ + d0;
        uint4 vraw = *(const uint4*)(Vb + gidx);
        const unsigned short* vp = (const unsigned short*)&vraw;
        #pragma unroll
        for (int j = 0; j < 8; j++) BufB[l * 68 + d0 + j] = bf2f(vp[j]);
    }
    __syncthreads();

    float og[4][4];
    #pragma unroll
    for (int r = 0; r < 4; r++)
        #pragma unroll
        for (int cc = 0; cc < 4; cc++) og[r][cc] = it[r][cc];

    for (int jl = 0; jl < CH_; jl++) {
        float scv[4], vv[4];
        ld4(&BufA[jl * 68 + i0], scv);
        ld4(&BufB[jl * 68 + j0], vv);
        #pragma unroll
        for (int r = 0; r < 4; r++)
            #pragma unroll
            for (int cc = 0; cc < 4; cc++) og[r][cc] += scv[r] * vv[cc];
    }
    #pragma unroll
    for (int r = 0; r < 4; r++) {
        int i = i0 + r;
        float rcp = 1.0f / den_l[i];
        size_t gidx = (size_t)(b * T_ + t0 + i) * HD_ + h * DK_ + j0;
        ushort4 graw = *(const ushort4*)(Gb + gidx);
        ushort4 o;
        o.x = f2bf(og[r][0] * rcp * bf2f(graw.x));
        o.y = f2bf(og[r][1] * rcp * bf2f(graw.y));
        o.z = f2bf(og[r][2] * rcp * bf2f(graw.z));
        o.w = f2bf(og[r][3] * rcp * bf2f(graw.w));
        *(ushort4*)(OGb + gidx) = o;
    }
}

// ---------------- host ----------------
extern "C" void kernel_launch(void* const* d_in, const int* in_sizes, int n_in,
                              void* d_out, int out_size, void* d_ws, size_t ws_size,
                              hipStream_t stream)
{
    (void)in_sizes; (void)n_in; (void)out_size; (void)ws_size;
    const float* x         = (const float*)d_in[0];
    const float* W_Q       = (const float*)d_in[1];
    const float* W_K       = (const float*)d_in[2];
    const float* W_V       = (const float*)d_in[3];
    const float* W_gw      = (const float*)d_in[4];
    const float* W_gb      = (const float*)d_in[5];
    const float* W_O       = (const float*)d_in[6];
    const float* decay_log = (const float*)d_in[7];
    float* y = (float*)d_out;

    char* ws = (char*)d_ws;
    size_t off = 0;
    auto alloc = [&](size_t bytes) { void* p = ws + off; off += (bytes + 255) & ~(size_t)255; return p; };
    unsigned short* xb   = (unsigned short*)alloc((size_t)B_ * T_ * D_ * 2);
    unsigned short* wqb  = (unsigned short*)alloc((size_t)HD_ * D_ * 2);
    unsigned short* wkb  = (unsigned short*)alloc((size_t)HD_ * D_ * 2);
    unsigned short* wvb  = (unsigned short*)alloc((size_t)HD_ * D_ * 2);
    unsigned short* wgb  = (unsigned short*)alloc((size_t)HD_ * D_ * 2);
    unsigned short* wob  = (unsigned short*)alloc((size_t)D_ * HD_ * 2);
    unsigned short* qb   = (unsigned short*)alloc((size_t)B_ * T_ * HD_ * 2);
    unsigned short* kb   = (unsigned short*)alloc((size_t)B_ * T_ * HD_ * 2);
    unsigned short* vb   = (unsigned short*)alloc((size_t)B_ * T_ * HD_ * 2);
    unsigned short* gb   = (unsigned short*)alloc((size_t)B_ * T_ * HD_ * 2);
    unsigned short* ogb  = (unsigned short*)alloc((size_t)B_ * T_ * HD_ * 2);
    float* Ssum = (float*)alloc((size_t)B_ * H_ * NC_ * DK_ * DK_ * 4);
    float* zsum = (float*)alloc((size_t)B_ * H_ * NC_ * DK_ * 4);

    k_cvt_all<<<8192 + 5 * 512, 256, 0, stream>>>(x, W_Q, W_K, W_V, W_gw, W_O,
                                                  xb, wqb, wkb, wvb, wgb, wob);
    k_gemm_qkvg<<<1024, 256, 0, stream>>>(xb, wqb, wkb, wvb, wgb, W_gb, qb, kb, vb, gb);
    k_chunk_sums<<<B_ * H_ * NC_, 256, 0, stream>>>(kb, vb, Ssum, zsum, decay_log);
    k_chunk_out<<<B_ * H_ * NC_, 256, 0, stream>>>(qb, kb, vb, gb, Ssum, zsum, ogb, decay_log);
    k_gemm_out<<<512, 256, 0, stream>>>(ogb, wob, y);
}

// Round 8
// 222.023 us; speedup vs baseline: 1.1083x; 1.0941x over previous
//
#include <hip/hip_runtime.h>
#include <cstdint>
#include <cstddef>

#define B_   4
#define T_   2048
#define D_   1024
#define H_   8
#define DK_  64
#define HD_  512      // H*DK
#define CH_  64       // chunk length
#define NC_  32       // T_/CH_
#define EPS_ 1e-6f

typedef __attribute__((ext_vector_type(4))) float f32x4;
typedef __attribute__((ext_vector_type(8))) short s16x8;

__device__ __forceinline__ unsigned short f2bf(float f) {
    unsigned int x = __float_as_uint(f);
    unsigned int r = (x + 0x7FFFu + ((x >> 16) & 1u)) >> 16;
    return (unsigned short)r;
}
__device__ __forceinline__ float bf2f(unsigned short u) {
    return __uint_as_float(((unsigned int)u) << 16);
}
// async global->LDS, 16B per lane; LDS dest = wave-uniform base + lane*16
__device__ __forceinline__ void gl_lds16(const unsigned short* g, unsigned short* l) {
    __builtin_amdgcn_global_load_lds(
        (const __attribute__((address_space(1))) unsigned int*)g,
        (__attribute__((address_space(3))) unsigned int*)l, 16, 0, 0);
}

// ---------------- K0: fused fp32 -> bf16 convert for all six tensors ----------------
__global__ __launch_bounds__(256) void k_cvt_all(
    const float* __restrict__ x,
    const float* __restrict__ wq, const float* __restrict__ wk,
    const float* __restrict__ wv, const float* __restrict__ wgw,
    const float* __restrict__ wo,
    unsigned short* __restrict__ xb,
    unsigned short* __restrict__ wqb, unsigned short* __restrict__ wkb,
    unsigned short* __restrict__ wvb, unsigned short* __restrict__ wgb,
    unsigned short* __restrict__ wob)
{
    int bid = blockIdx.x;
    const float* src; unsigned short* dst; int idx;
    if (bid < 8192) {
        src = x; dst = xb; idx = bid * 256 + threadIdx.x;
    } else {
        int r = bid - 8192;
        int w = r >> 9;
        idx = (r & 511) * 256 + threadIdx.x;
        switch (w) {
            case 0:  src = wq;  dst = wqb; break;
            case 1:  src = wk;  dst = wkb; break;
            case 2:  src = wv;  dst = wvb; break;
            case 3:  src = wgw; dst = wgb; break;
            default: src = wo;  dst = wob; break;
        }
    }
    float4 v = ((const float4*)src)[idx];
    ushort4 o;
    o.x = f2bf(v.x); o.y = f2bf(v.y); o.z = f2bf(v.z); o.w = f2bf(v.w);
    ((ushort4*)dst)[idx] = o;
}

// ---------------- K1: fused QKVG GEMM (round-4 proven config) ----------------
#define GT_M 128
#define GT_N 128
#define GBK  64
#define LDA  64   // unpadded: required by global_load_lds; XOR swizzle kills conflicts

__global__ __launch_bounds__(256) void k_gemm_qkvg(
    const unsigned short* __restrict__ xb,
    const unsigned short* __restrict__ wqb, const unsigned short* __restrict__ wkb,
    const unsigned short* __restrict__ wvb, const unsigned short* __restrict__ wgb,
    const float* __restrict__ bias,
    unsigned short* __restrict__ qo, unsigned short* __restrict__ ko,
    unsigned short* __restrict__ vo, unsigned short* __restrict__ go)
{
    __shared__ unsigned short As[GT_M * LDA];
    __shared__ unsigned short Bs[GT_N * LDA];
    const int tid = threadIdx.x;
    const int id  = blockIdx.x;
    const int xcd = id & 7, per = id >> 3;
    const int mtile = xcd * 8 + (per & 7);       // 0..63
    const int combo = per >> 3;                  // 0..15
    const int which = combo >> 2;                // 0=Q 1=K 2=V 3=G
    const int nb    = combo & 3;
    const int m0    = mtile * GT_M;
    const int n0    = nb * GT_N;                 // within [0,512)
    const unsigned short* Wp = (which == 0) ? wqb : (which == 1) ? wkb : (which == 2) ? wvb : wgb;
    unsigned short* Op       = (which == 0) ? qo  : (which == 1) ? ko  : (which == 2) ? vo  : go;
    const int K = D_;

    const int lane = tid & 63, wave = tid >> 6;
    const int wm = (wave >> 1) * 64, wn = (wave & 1) * 64;
    const int r16 = lane & 15, quad = lane >> 4;
    const int lrow = lane >> 3, lseg = lane & 7;
    const int sseg = lseg ^ lrow;                  // XOR swizzle
    const int rx   = r16 & 7;                      // read-side swizzle key

    f32x4 acc[4][4];
    #pragma unroll
    for (int a = 0; a < 4; a++)
        #pragma unroll
        for (int b = 0; b < 4; b++) acc[a][b] = 0.0f;

    for (int ko_ = 0; ko_ < K; ko_ += GBK) {
        #pragma unroll
        for (int i = 0; i < 4; i++) {
            int chunk = wave * 4 + i;            // 0..15, wave-uniform
            int row = chunk * 8 + lrow;
            gl_lds16(xb + (size_t)(m0 + row) * K + ko_ + sseg * 8, As + chunk * 512);
            gl_lds16(Wp + (size_t)(n0 + row) * K + ko_ + sseg * 8, Bs + chunk * 512);
        }
        __syncthreads();
        #pragma unroll
        for (int kk = 0; kk < GBK; kk += 32) {
            const int gb_ = kk >> 3;
            const int goff = (((gb_ + quad) ^ rx) << 3);
            s16x8 af[4], bf[4];
            #pragma unroll
            for (int mt = 0; mt < 4; mt++)
                af[mt] = *(const s16x8*)&As[(wm + mt * 16 + r16) * LDA + goff];
            #pragma unroll
            for (int nt = 0; nt < 4; nt++)
                bf[nt] = *(const s16x8*)&Bs[(wn + nt * 16 + r16) * LDA + goff];
            #pragma unroll
            for (int mt = 0; mt < 4; mt++)
                #pragma unroll
                for (int nt = 0; nt < 4; nt++)
                    acc[mt][nt] = __builtin_amdgcn_mfma_f32_16x16x32_bf16(af[mt], bf[nt], acc[mt][nt], 0, 0, 0);
        }
        __syncthreads();
    }
    #pragma unroll
    for (int mt = 0; mt < 4; mt++) {
        #pragma unroll
        for (int nt = 0; nt < 4; nt++) {
            int col = n0 + wn + nt * 16 + r16;
            float bv = (which == 3) ? bias[col] : 0.0f;
            #pragma unroll
            for (int r = 0; r < 4; r++) {
                int row = m0 + wm + mt * 16 + quad * 4 + r;
                float v = acc[mt][nt][r];
                if (which <= 1)      v = (v > 0.0f) ? v + 1.0f : __builtin_expf(v);     // phi = elu+1
                else if (which == 3) v = 1.0f / (1.0f + __builtin_expf(-(v + bv)));     // sigmoid gate
                Op[(size_t)row * HD_ + col] = f2bf(v);
            }
        }
    }
}

// ---------------- K5: output GEMM: Y = OG @ W_O^T (fp32 out), round-4 config ----------------
__global__ __launch_bounds__(256) void k_gemm_out(
    const unsigned short* __restrict__ ogb, const unsigned short* __restrict__ wob,
    float* __restrict__ y)
{
    __shared__ unsigned short As[GT_M * LDA];
    __shared__ unsigned short Bs[GT_N * LDA];
    const int tid = threadIdx.x;
    const int id  = blockIdx.x;
    const int xcd = id & 7, per = id >> 3;
    const int m0 = (xcd * 8 + (per & 7)) * GT_M;
    const int n0 = (per >> 3) * GT_N;            // 0..7 n-tiles (D_=1024)
    const int K = HD_;   // 512

    const int lane = tid & 63, wave = tid >> 6;
    const int wm = (wave >> 1) * 64, wn = (wave & 1) * 64;
    const int r16 = lane & 15, quad = lane >> 4;
    const int lrow = lane >> 3, lseg = lane & 7;
    const int sseg = lseg ^ lrow;
    const int rx   = r16 & 7;

    f32x4 acc[4][4];
    #pragma unroll
    for (int a = 0; a < 4; a++)
        #pragma unroll
        for (int b = 0; b < 4; b++) acc[a][b] = 0.0f;

    for (int ko_ = 0; ko_ < K; ko_ += GBK) {
        #pragma unroll
        for (int i = 0; i < 4; i++) {
            int chunk = wave * 4 + i;
            int row = chunk * 8 + lrow;
            gl_lds16(ogb + (size_t)(m0 + row) * K + ko_ + sseg * 8, As + chunk * 512);
            gl_lds16(wob + (size_t)(n0 + row) * K + ko_ + sseg * 8, Bs + chunk * 512);
        }
        __syncthreads();
        #pragma unroll
        for (int kk = 0; kk < GBK; kk += 32) {
            const int gb_ = kk >> 3;
            const int goff = (((gb_ + quad) ^ rx) << 3);
            s16x8 af[4], bf[4];
            #pragma unroll
            for (int mt = 0; mt < 4; mt++)
                af[mt] = *(const s16x8*)&As[(wm + mt * 16 + r16) * LDA + goff];
            #pragma unroll
            for (int nt = 0; nt < 4; nt++)
                bf[nt] = *(const s16x8*)&Bs[(wn + nt * 16 + r16) * LDA + goff];
            #pragma unroll
            for (int mt = 0; mt < 4; mt++)
                #pragma unroll
                for (int nt = 0; nt < 4; nt++)
                    acc[mt][nt] = __builtin_amdgcn_mfma_f32_16x16x32_bf16(af[mt], bf[nt], acc[mt][nt], 0, 0, 0);
        }
        __syncthreads();
    }
    #pragma unroll
    for (int mt = 0; mt < 4; mt++)
        #pragma unroll
        for (int nt = 0; nt < 4; nt++) {
            int col = n0 + wn + nt * 16 + r16;
            #pragma unroll
            for (int r = 0; r < 4; r++) {
                int row = m0 + wm + mt * 16 + quad * 4 + r;
                y[(size_t)row * D_ + col] = acc[mt][nt][r];
            }
        }
}

// ---------------- K2: per-chunk decayed sums via MFMA ----------------
// Ssum[bh,c][i][j] = sum_l gamma^(CH-1-l) k_l[i] v_l[j];  zsum[d] likewise.
#define LDB 72   // bf16 row stride for 64-col LDS tiles (144B: benign banks, 16B-aligned rows)

__global__ __launch_bounds__(256) void k_chunk_sums(
    const unsigned short* __restrict__ Kb, const unsigned short* __restrict__ Vb,
    float* __restrict__ Ssum, float* __restrict__ zsum, const float* __restrict__ decay_log)
{
    __shared__ unsigned short kT[CH_ * LDB];  // [d][l], decay weight folded
    __shared__ unsigned short vT[CH_ * LDB];  // [j][l]
    const int tid = threadIdx.x;
    const int bc  = blockIdx.x;            // bh*NC_ + c
    const int c   = bc & (NC_ - 1);
    const int bh  = bc >> 5;
    const int h   = bh & (H_ - 1);
    const int b   = bh >> 3;
    const float g  = 1.0f / (1.0f + __builtin_expf(-decay_log[h]));
    const float lg = __builtin_log2f(g);
    const int t0 = c * CH_;

    #pragma unroll
    for (int e = 0; e < 2; e++) {
        int lid = e * 256 + tid;           // 64 rows x 8 segs
        int l = lid >> 3, d0 = (lid & 7) * 8;
        float w = __builtin_exp2f((float)(CH_ - 1 - l) * lg);
        size_t gidx = (size_t)(b * T_ + t0 + l) * HD_ + h * DK_ + d0;
        uint4 kraw = *(const uint4*)(Kb + gidx);
        uint4 vraw = *(const uint4*)(Vb + gidx);
        const unsigned short* kp = (const unsigned short*)&kraw;
        const unsigned short* vp = (const unsigned short*)&vraw;
        #pragma unroll
        for (int j = 0; j < 8; j++) {
            kT[(d0 + j) * LDB + l] = f2bf(bf2f(kp[j]) * w);
            vT[(d0 + j) * LDB + l] = vp[j];
        }
    }
    __syncthreads();

    const int lane = tid & 63, wave = tid >> 6;
    const int r16 = lane & 15, quad = lane >> 4;
    const int wm = wave * 16;              // wave tile 16x64

    f32x4 acc[4];
    #pragma unroll
    for (int nt = 0; nt < 4; nt++) acc[nt] = 0.0f;
    #pragma unroll
    for (int ls_ = 0; ls_ < CH_; ls_ += 32) {
        s16x8 a = *(const s16x8*)&kT[(wm + r16) * LDB + ls_ + quad * 8];
        #pragma unroll
        for (int nt = 0; nt < 4; nt++) {
            s16x8 bv = *(const s16x8*)&vT[(nt * 16 + r16) * LDB + ls_ + quad * 8];
            acc[nt] = __builtin_amdgcn_mfma_f32_16x16x32_bf16(a, bv, acc[nt], 0, 0, 0);
        }
    }
    size_t base = (size_t)bc * (DK_ * DK_);
    #pragma unroll
    for (int nt = 0; nt < 4; nt++)
        #pragma unroll
        for (int r = 0; r < 4; r++)
            Ssum[base + (size_t)(wm + quad * 4 + r) * DK_ + nt * 16 + r16] = acc[nt][r];

    if (tid < DK_) {
        float s = 0.0f;
        for (int l = 0; l < CH_; l++) s += bf2f(kT[tid * LDB + l]);
        zsum[(size_t)bc * DK_ + tid] = s;
    }
}

// ---------------- K4: per-chunk outputs via MFMA (scan fused via Horner) ----------------
__global__ __launch_bounds__(256) void k_chunk_out(
    const unsigned short* __restrict__ Qb, const unsigned short* __restrict__ Kb,
    const unsigned short* __restrict__ Vb, const unsigned short* __restrict__ Gb,
    const float* __restrict__ Ssum, const float* __restrict__ zsum,
    unsigned short* __restrict__ OGb, const float* __restrict__ decay_log)
{
    __shared__ unsigned short qs[CH_ * LDB];   // [i][d] natural
    __shared__ unsigned short ks_l[CH_ * LDB]; // [j][d] natural
    __shared__ unsigned short SpT[CH_ * LDB];  // [j][d] = S_prev^T; reused as ScL [i][l]
    __shared__ unsigned short vT[CH_ * LDB];   // [j][l] = v^T
    __shared__ float den_l[CH_];
    __shared__ float zp_l[DK_];
    __shared__ float gpow[CH_ + 1];

    const int tid = threadIdx.x;
    const int bc  = blockIdx.x;
    const int c   = bc & (NC_ - 1);
    const int bh  = bc >> 5;
    const int h   = bh & (H_ - 1);
    const int b   = bh >> 3;
    const float g  = 1.0f / (1.0f + __builtin_expf(-decay_log[h]));
    const float lg = __builtin_log2f(g);
    const float gC = __builtin_exp2f((float)CH_ * lg);   // gamma^CH
    const int t0 = c * CH_;

    if (tid <= CH_) gpow[tid] = __builtin_exp2f((float)tid * lg);

    // stage q,k natural (vectorized), v transposed (scalar)
    #pragma unroll
    for (int e = 0; e < 2; e++) {
        int lid = e * 256 + tid;
        int l = lid >> 3, d0 = (lid & 7) * 8;
        size_t gidx = (size_t)(b * T_ + t0 + l) * HD_ + h * DK_ + d0;
        uint4 qraw = *(const uint4*)(Qb + gidx);
        uint4 kraw = *(const uint4*)(Kb + gidx);
        uint4 vraw = *(const uint4*)(Vb + gidx);
        *(uint4*)&qs[l * LDB + d0]   = qraw;
        *(uint4*)&ks_l[l * LDB + d0] = kraw;
        const unsigned short* vp = (const unsigned short*)&vraw;
        #pragma unroll
        for (int j = 0; j < 8; j++) vT[(d0 + j) * LDB + l] = vp[j];
    }
    // Horner exclusive prefix: S_prev = sum_{c'<c} gC^(c-1-c') Ssum[c'], write transposed bf16
    {
        f32x4 sp[4];
        #pragma unroll
        for (int q = 0; q < 4; q++) sp[q] = 0.0f;
        const int flat = tid * 16;
        for (int cp = 0; cp < c; cp++) {
            const float* src = Ssum + (size_t)(bh * NC_ + cp) * 4096 + flat;
            #pragma unroll
            for (int q = 0; q < 4; q++) {
                f32x4 v = *(const f32x4*)(src + q * 4);
                sp[q] = sp[q] * gC + v;
            }
        }
        int row = tid >> 2, col0 = (tid & 3) * 16;   // row = d, col = j
        #pragma unroll
        for (int q = 0; q < 4; q++)
            #pragma unroll
            for (int e = 0; e < 4; e++)
                SpT[(col0 + q * 4 + e) * LDB + row] = f2bf(sp[q][e]);
    }
    if (tid < DK_) {
        float zp = 0.0f;
        for (int cp = 0; cp < c; cp++)
            zp = zp * gC + zsum[(size_t)(bh * NC_ + cp) * DK_ + tid];
        zp_l[tid] = zp;
    }
    __syncthreads();   // S1: staging complete

    const int lane = tid & 63, wave = tid >> 6;
    const int r16 = lane & 15, quad = lane >> 4;
    const int wm = wave * 16;              // wave tile 16x64

    // phase 1: P = q k^T ; IT = q S_prev  (both C-layout)
    f32x4 P[4], IT[4];
    #pragma unroll
    for (int nt = 0; nt < 4; nt++) { P[nt] = 0.0f; IT[nt] = 0.0f; }
    #pragma unroll
    for (int ks_ = 0; ks_ < DK_; ks_ += 32) {
        s16x8 a = *(const s16x8*)&qs[(wm + r16) * LDB + ks_ + quad * 8];
        #pragma unroll
        for (int nt = 0; nt < 4; nt++) {
            s16x8 bk = *(const s16x8*)&ks_l[(nt * 16 + r16) * LDB + ks_ + quad * 8];
            P[nt] = __builtin_amdgcn_mfma_f32_16x16x32_bf16(a, bk, P[nt], 0, 0, 0);
            s16x8 bs = *(const s16x8*)&SpT[(nt * 16 + r16) * LDB + ks_ + quad * 8];
            IT[nt] = __builtin_amdgcn_mfma_f32_16x16x32_bf16(a, bs, IT[nt], 0, 0, 0);
        }
    }
    __syncthreads();   // S2: all SpT reads done; safe to overwrite with ScL

    // mask + decay, write Sc into SpT buffer (natural [i][l]), row sums
    float rowsum[4] = {0.f, 0.f, 0.f, 0.f};
    #pragma unroll
    for (int nt = 0; nt < 4; nt++) {
        #pragma unroll
        for (int r = 0; r < 4; r++) {
            int i = wm + quad * 4 + r, j = nt * 16 + r16;
            float s = (j <= i) ? P[nt][r] * gpow[i - j] : 0.0f;
            rowsum[r] += s;
            SpT[i * LDB + j] = f2bf(s);
            IT[nt][r] *= gpow[i + 1];
        }
    }
    #pragma unroll
    for (int r = 0; r < 4; r++) {
        float rs = rowsum[r];
        rs += __shfl_xor(rs, 1);
        rs += __shfl_xor(rs, 2);
        rs += __shfl_xor(rs, 4);
        rs += __shfl_xor(rs, 8);
        if (r16 == 0) den_l[wm + quad * 4 + r] = rs;
    }
    __syncthreads();   // S3: ScL + den intra visible

    if (tid < DK_) {   // den += gamma^(i+1) q_i . z_prev + eps
        float dp = 0.0f;
        for (int d = 0; d < DK_; d++) dp += bf2f(qs[tid * LDB + d]) * zp_l[d];
        den_l[tid] += gpow[tid + 1] * dp + EPS_;
    }
    // phase 2: O = IT + Sc @ v
    f32x4 O[4];
    #pragma unroll
    for (int nt = 0; nt < 4; nt++) O[nt] = IT[nt];
    #pragma unroll
    for (int ls_ = 0; ls_ < CH_; ls_ += 32) {
        s16x8 a = *(const s16x8*)&SpT[(wm + r16) * LDB + ls_ + quad * 8];
        #pragma unroll
        for (int nt = 0; nt < 4; nt++) {
            s16x8 bv = *(const s16x8*)&vT[(nt * 16 + r16) * LDB + ls_ + quad * 8];
            O[nt] = __builtin_amdgcn_mfma_f32_16x16x32_bf16(a, bv, O[nt], 0, 0, 0);
        }
    }
    __syncthreads();   // S4: den final

    #pragma unroll
    for (int nt = 0; nt < 4; nt++) {
        #pragma unroll
        for (int r = 0; r < 4; r++) {
            int i = wm + quad * 4 + r, j = nt * 16 + r16;
            size_t gidx = (size_t)(b * T_ + t0 + i) * HD_ + h * DK_ + j;
            float val = O[nt][r] / den_l[i] * bf2f(Gb[gidx]);
            OGb[gidx] = f2bf(val);
        }
    }
}

// ---------------- host ----------------
extern "C" void kernel_launch(void* const* d_in, const int* in_sizes, int n_in,
                              void* d_out, int out_size, void* d_ws, size_t ws_size,
                              hipStream_t stream)
{
    (void)in_sizes; (void)n_in; (void)out_size; (void)ws_size;
    const float* x         = (const float*)d_in[0];
    const float* W_Q       = (const float*)d_in[1];
    const float* W_K       = (const float*)d_in[2];
    const float* W_V       = (const float*)d_in[3];
    const float* W_gw      = (const float*)d_in[4];
    const float* W_gb      = (const float*)d_in[5];
    const float* W_O       = (const float*)d_in[6];
    const float* decay_log = (const float*)d_in[7];
    float* y = (float*)d_out;

    char* ws = (char*)d_ws;
    size_t off = 0;
    auto alloc = [&](size_t bytes) { void* p = ws + off; off += (bytes + 255) & ~(size_t)255; return p; };
    unsigned short* xb   = (unsigned short*)alloc((size_t)B_ * T_ * D_ * 2);
    unsigned short* wqb  = (unsigned short*)alloc((size_t)HD_ * D_ * 2);
    unsigned short* wkb  = (unsigned short*)alloc((size_t)HD_ * D_ * 2);
    unsigned short* wvb  = (unsigned short*)alloc((size_t)HD_ * D_ * 2);
    unsigned short* wgb  = (unsigned short*)alloc((size_t)HD_ * D_ * 2);
    unsigned short* wob  = (unsigned short*)alloc((size_t)D_ * HD_ * 2);
    unsigned short* qb   = (unsigned short*)alloc((size_t)B_ * T_ * HD_ * 2);
    unsigned short* kb   = (unsigned short*)alloc((size_t)B_ * T_ * HD_ * 2);
    unsigned short* vb   = (unsigned short*)alloc((size_t)B_ * T_ * HD_ * 2);
    unsigned short* gb   = (unsigned short*)alloc((size_t)B_ * T_ * HD_ * 2);
    unsigned short* ogb  = (unsigned short*)alloc((size_t)B_ * T_ * HD_ * 2);
    float* Ssum = (float*)alloc((size_t)B_ * H_ * NC_ * DK_ * DK_ * 4);
    float* zsum = (float*)alloc((size_t)B_ * H_ * NC_ * DK_ * 4);

    k_cvt_all<<<8192 + 5 * 512, 256, 0, stream>>>(x, W_Q, W_K, W_V, W_gw, W_O,
                                                  xb, wqb, wkb, wvb, wgb, wob);
    k_gemm_qkvg<<<1024, 256, 0, stream>>>(xb, wqb, wkb, wvb, wgb, W_gb, qb, kb, vb, gb);
    k_chunk_sums<<<B_ * H_ * NC_, 256, 0, stream>>>(kb, vb, Ssum, zsum, decay_log);
    k_chunk_out<<<B_ * H_ * NC_, 256, 0, stream>>>(qb, kb, vb, gb, Ssum, zsum, ogb, decay_log);
    k_gemm_out<<<512, 256, 0, stream>>>(ogb, wob, y);
}